// Round 14
// baseline (195.420 us; speedup 1.0000x reference)
//
#include <hip/hip_runtime.h>
#include <hip/hip_bf16.h>

#define D_MODEL 256
#define N_HEADS 8
#define HD 32
#define NQ 900
#define BS 4
#define MROWS (NQ * BS)          // 3600
#define HW_TOT 21760
#define VROWS (HW_TOT * BS)      // 87040

typedef __attribute__((ext_vector_type(8))) short bf16x8;
typedef __attribute__((ext_vector_type(4))) float f32x4;

__device__ inline short f2b(float f) {
  union { __hip_bfloat16 h; short s; } u;
  u.h = __float2bfloat16(f);
  return u.s;
}
__device__ inline float bu2f(unsigned short u) {
  union { unsigned int i; float f; } c;
  c.i = ((unsigned int)u) << 16;
  return c.f;
}
__device__ inline bf16x8 bzero8() {
  bf16x8 v;
#pragma unroll
  for (int j = 0; j < 8; ++j) v[j] = 0;
  return v;
}
__device__ inline f32x4 fzero4() {
  f32x4 v;
#pragma unroll
  for (int j = 0; j < 4; ++j) v[j] = 0.f;
  return v;
}

// async global->LDS, 16B per lane: lds dest = base + lane*16 (wave-uniform base)
#define GLL16(gsrc, ldst)                                                     \
  __builtin_amdgcn_global_load_lds(                                           \
      (__attribute__((address_space(1))) void*)(gsrc),                        \
      (__attribute__((address_space(3))) void*)(ldst), 16, 0, 0)

// ------------------------------------------------ prep: weights + activations
__global__ __launch_bounds__(256) void prep_all(const float* __restrict__ s0,
                                                const float* __restrict__ s1,
                                                const float* __restrict__ s2,
                                                const float* __restrict__ s3,
                                                const float* __restrict__ s4,
                                                const float* __restrict__ s5,
                                                const float* __restrict__ s6,
                                                const float* __restrict__ s7,
                                                short* __restrict__ dst,
                                                const float* __restrict__ tgt,
                                                const float* __restrict__ qpos,
                                                short* __restrict__ tgtb,
                                                short* __restrict__ qkb,
                                                const float* __restrict__ so_b,
                                                const float* __restrict__ aw_b,
                                                float* __restrict__ biasSOAW) {
  int i = blockIdx.x * 256 + threadIdx.x;
  if (i < 1540096) {
    const float* s; int off;
    if (i < 196608)      { s = s0; off = 0; }
    else if (i < 262144) { s = s1; off = 196608; }
    else if (i < 327680) { s = s2; off = 262144; }
    else if (i < 360448) { s = s3; off = 327680; }
    else if (i < 425984) { s = s4; off = 360448; }
    else if (i < 491520) { s = s5; off = 425984; }
    else if (i < 1015808){ s = s6; off = 491520; }
    else                 { s = s7; off = 1015808; }
    dst[i] = f2b(s[i - off]);
  } else {
    int j = i - 1540096;  // < 921600
    float t = tgt[j], p = qpos[j];
    tgtb[j] = f2b(t);
    qkb[j] = f2b(t + p);
    if (j < 384) biasSOAW[j] = (j < 256) ? so_b[j] : aw_b[j - 256];
  }
}

// ------------------------------------------------ GEMM core (BM=64, gll staging)
template <int BN, int AF32, int OUTF32, int RELU>
__device__ __forceinline__ void gemm_core(const void* __restrict__ Xv,
                                          const short* __restrict__ W,
                                          const float* __restrict__ bias,
                                          void* __restrict__ outv,
                                          int M, int N, int K, int m0, int n0,
                                          int t0, int t1, int addBias,
                                          short* __restrict__ smem) {
  constexpr int NF = BN / 16;
  short* sA = smem;                // 2 x 64*32
  short* sB = smem + 2 * 2048;     // 2 x BN*32
  const int tid = threadIdx.x;
  const int wave = tid >> 6, lane = tid & 63;
  const int l15 = lane & 15, l4 = lane >> 4;
  const int wr = wave * 16;
  const float* Xf = (const float*)Xv;
  const short* Xh = (const short*)Xv;

  f32x4 acc[NF];
#pragma unroll
  for (int f = 0; f < NF; ++f) acc[f] = fzero4();

  const int alr = wave * 16 + (lane >> 2);
  const int ags = (lane & 3) ^ ((alr >> 1) & 3);
  const int arow = tid >> 2, ak = tid & 3;
  const int agsrc = ak ^ ((arow >> 1) & 3);
  float4 ra0, ra1;

  auto stageB = [&](int t, int buf) {
    short* bb = sB + buf * BN * 32;
#pragma unroll
    for (int j = 0; j < BN / 64; ++j) {
      int lr = j * 64 + alr;
      int gs = (lane & 3) ^ ((lr >> 1) & 3);
      const short* src = W + (size_t)(n0 + lr) * K + t * 32 + gs * 8;
      GLL16(src, bb + (j * 64 + wave * 16) * 32);
    }
  };
  auto stageA_gll = [&](int t, int buf) {
    const short* src = Xh + (size_t)(m0 + alr) * K + t * 32 + ags * 8;
    GLL16(src, sA + buf * 2048 + wave * 512);
  };
  auto loadA_f32 = [&](int t) {
    const float* p = Xf + (size_t)(m0 + arow) * K + t * 32 + agsrc * 8;
    ra0 = *reinterpret_cast<const float4*>(p);
    ra1 = *reinterpret_cast<const float4*>(p + 4);
  };
  auto writeA_f32 = [&](int buf) {
    bf16x8 v;
    v[0] = f2b(ra0.x); v[1] = f2b(ra0.y); v[2] = f2b(ra0.z); v[3] = f2b(ra0.w);
    v[4] = f2b(ra1.x); v[5] = f2b(ra1.y); v[6] = f2b(ra1.z); v[7] = f2b(ra1.w);
    *reinterpret_cast<bf16x8*>(&sA[buf * 2048 + arow * 32 + ak * 8]) = v;
  };
  auto compute = [&](int buf) {
    const int r = wr + l15;
    bf16x8 av = *reinterpret_cast<const bf16x8*>(
        &sA[buf * 2048 + r * 32 + ((l4 ^ ((r >> 1) & 3)) * 8)]);
#pragma unroll
    for (int f = 0; f < NF; ++f) {
      const int rb = f * 16 + l15;
      bf16x8 bv = *reinterpret_cast<const bf16x8*>(
          &sB[buf * BN * 32 + rb * 32 + ((l4 ^ ((rb >> 1) & 3)) * 8)]);
      acc[f] = __builtin_amdgcn_mfma_f32_16x16x32_bf16(av, bv, acc[f], 0, 0, 0);
    }
  };

  if constexpr (AF32) { loadA_f32(t0); writeA_f32(0); }
  else stageA_gll(t0, 0);
  stageB(t0, 0);
  __syncthreads();

  int buf = 0;
  for (int t = t0; t < t1; ++t) {
    if (t + 1 < t1) {
      if constexpr (AF32) loadA_f32(t + 1);
      else stageA_gll(t + 1, buf ^ 1);
      stageB(t + 1, buf ^ 1);
    }
    compute(buf);
    if (AF32 && t + 1 < t1) writeA_f32(buf ^ 1);
    __syncthreads();
    buf ^= 1;
  }

#pragma unroll
  for (int f = 0; f < NF; ++f) {
    int col = n0 + f * 16 + l15;
    float bfv = addBias ? bias[col] : 0.f;
#pragma unroll
    for (int i = 0; i < 4; ++i) {
      int row = m0 + wr + l4 * 4 + i;
      if (row >= M) continue;
      float v = acc[f][i] + bfv;
      if (RELU) v = fmaxf(v, 0.f);
      if constexpr (OUTF32)
        ((float*)outv)[(size_t)row * N + col] = v;
      else
        ((short*)outv)[(size_t)row * N + col] = f2b(v);
    }
  }
}

template <int BN, int AF32, int OUTF32, int RELU>
__global__ __launch_bounds__(256) void gemm2(const void* __restrict__ Xv,
                                             const short* __restrict__ W,
                                             const float* __restrict__ bias,
                                             void* __restrict__ outv,
                                             int M, int N, int K) {
  __shared__ __align__(16) short smem[2 * 2048 + 2 * BN * 32];
  gemm_core<BN, AF32, OUTF32, RELU>(Xv, W, bias, outv, M, N, K,
                                    blockIdx.x * 64, blockIdx.y * BN,
                                    0, K / 32, 1, smem);
}

// ff2 split-K: blockIdx.z = K-chunk; writes fp32 partials (bias only in chunk 0)
__global__ __launch_bounds__(256) void gemm_splitk(const void* __restrict__ Xv,
                                                   const short* __restrict__ W,
                                                   const float* __restrict__ bias,
                                                   float* __restrict__ outp,
                                                   int M, int N, int K) {
  __shared__ __align__(16) short smem[2 * 2048 + 2 * 64 * 32];
  const int kc = blockIdx.z;
  const int ntc = K / 32 / 4;
  gemm_core<64, 0, 1, 0>(Xv, W, bias, outp + (size_t)kc * M * N, M, N, K,
                         blockIdx.x * 64, blockIdx.y * 64,
                         kc * ntc, (kc + 1) * ntc, kc == 0, smem);
}

// ------------------------------------------------ fused GEMM(BN=256) + residual + LN
// One block = 64 rows, full 256 cols -> LN is row/wave-local (16-lane shfl reduce).
// outF = LN(X@W^T + bias + R); outB (optional) = bf16(outF + addv).
__global__ __launch_bounds__(256) void gemm_ln(const short* __restrict__ X,
                                               const short* __restrict__ W,
                                               const float* __restrict__ bias,
                                               const float* __restrict__ R,
                                               const float* __restrict__ g,
                                               const float* __restrict__ bvec,
                                               float* __restrict__ outF,
                                               short* __restrict__ outB,
                                               const float* __restrict__ addv) {
  __shared__ __align__(16) short smem[2 * 2048 + 2 * 8192];  // 40KB
  short* sA = smem;
  short* sB = smem + 2 * 2048;
  const int tid = threadIdx.x;
  const int wave = tid >> 6, lane = tid & 63;
  const int l15 = lane & 15, l4 = lane >> 4;
  const int wr = wave * 16;
  const int m0 = blockIdx.x * 64;

  f32x4 acc[16];
#pragma unroll
  for (int f = 0; f < 16; ++f) acc[f] = fzero4();

  const int alr = wave * 16 + (lane >> 2);
  const int ags = (lane & 3) ^ ((alr >> 1) & 3);

  auto stageA = [&](int t, int buf) {
    const short* src = X + (size_t)(m0 + alr) * 256 + t * 32 + ags * 8;
    GLL16(src, sA + buf * 2048 + wave * 512);
  };
  auto stageB = [&](int t, int buf) {
#pragma unroll
    for (int j = 0; j < 4; ++j) {
      int lr = j * 64 + alr;
      int gs = (lane & 3) ^ ((lr >> 1) & 3);
      const short* src = W + (size_t)lr * 256 + t * 32 + gs * 8;
      GLL16(src, sB + buf * 8192 + (j * 64 + wave * 16) * 32);
    }
  };
  auto compute = [&](int buf) {
    const int r = wr + l15;
    bf16x8 av = *reinterpret_cast<const bf16x8*>(
        &sA[buf * 2048 + r * 32 + ((l4 ^ ((r >> 1) & 3)) * 8)]);
#pragma unroll
    for (int f = 0; f < 16; ++f) {
      const int rb = f * 16 + l15;
      bf16x8 bv = *reinterpret_cast<const bf16x8*>(
          &sB[buf * 8192 + rb * 32 + ((l4 ^ ((rb >> 1) & 3)) * 8)]);
      acc[f] = __builtin_amdgcn_mfma_f32_16x16x32_bf16(av, bv, acc[f], 0, 0, 0);
    }
  };

  stageA(0, 0); stageB(0, 0);
  __syncthreads();
  int buf = 0;
  for (int t = 0; t < 8; ++t) {
    if (t + 1 < 8) { stageA(t + 1, buf ^ 1); stageB(t + 1, buf ^ 1); }
    compute(buf);
    __syncthreads();
    buf ^= 1;
  }

  // epilogue: + bias + residual, row-local LN
  float sum[4] = {0.f, 0.f, 0.f, 0.f}, sum2[4] = {0.f, 0.f, 0.f, 0.f};
#pragma unroll
  for (int f = 0; f < 16; ++f) {
    const int col = f * 16 + l15;
    const float bc = bias[col];
#pragma unroll
    for (int i = 0; i < 4; ++i) {
      const int row = m0 + wr + l4 * 4 + i;
      float r = (row < MROWS) ? R[(size_t)row * 256 + col] : 0.f;
      float v = acc[f][i] + bc + r;
      acc[f][i] = v;
      sum[i] += v;
      sum2[i] += v * v;
    }
  }
#pragma unroll
  for (int off = 1; off < 16; off <<= 1)
#pragma unroll
    for (int i = 0; i < 4; ++i) {
      sum[i] += __shfl_xor(sum[i], off);
      sum2[i] += __shfl_xor(sum2[i], off);
    }
  float mu[4], inv[4];
#pragma unroll
  for (int i = 0; i < 4; ++i) {
    mu[i] = sum[i] * (1.f / 256.f);
    float var = sum2[i] * (1.f / 256.f) - mu[i] * mu[i];
    inv[i] = rsqrtf(var + 1e-5f);
  }
#pragma unroll
  for (int f = 0; f < 16; ++f) {
    const int col = f * 16 + l15;
    const float gc = g[col], bc = bvec[col];
#pragma unroll
    for (int i = 0; i < 4; ++i) {
      const int row = m0 + wr + l4 * 4 + i;
      if (row >= MROWS) continue;
      float y = (acc[f][i] - mu[i]) * inv[i] * gc + bc;
      outF[(size_t)row * 256 + col] = y;
      if (outB)
        outB[(size_t)row * 256 + col] =
            f2b(y + (addv ? addv[(size_t)row * 256 + col] : 0.f));
    }
  }
}

// ------------------------------------------------ q|k and v projections, one dispatch
__global__ __launch_bounds__(256) void qkv_gemm(const short* __restrict__ qkb,
                                                const short* __restrict__ tgtb,
                                                const short* __restrict__ Wqkv,
                                                const float* __restrict__ sa_in_b,
                                                short* __restrict__ QKb,
                                                short* __restrict__ Vb) {
  __shared__ __align__(16) short smem[2 * 2048 + 2 * 64 * 32];
  int bx = blockIdx.x;
  if (bx < 456) {
    gemm_core<64, 0, 0, 0>(qkb, Wqkv, sa_in_b, QKb, MROWS, 512, 256,
                           (bx % 57) * 64, (bx / 57) * 64, 0, 8, 1, smem);
  } else {
    bx -= 456;
    gemm_core<64, 0, 0, 0>(tgtb, Wqkv + 512 * 256, sa_in_b + 512, Vb, MROWS, 256, 256,
                           (bx % 57) * 64, (bx / 57) * 64, 0, 8, 1, smem);
  }
}

// ------------------------------------------------ flash attention body v2
// LDS: sQ 2048 | sK 2x2048 | sVt 2x2304 | sP 4608  = 15360 shorts (30.7KB)
__device__ __forceinline__ void flash_body(const short* __restrict__ QK,
                                           const short* __restrict__ V,
                                           short* __restrict__ O,
                                           int bid, short* __restrict__ smem) {
  const int bh = bid & 31, b = bh >> 3, h = bh & 7;
  const int q0 = (bid >> 5) * 64;
  const int tid = threadIdx.x, wave = tid >> 6, lane = tid & 63;
  const int l15 = lane & 15, l4 = lane >> 4;
  const int cb = h * 32;

  short* sQ = smem;            // 64*32
  short* sK = smem + 2048;     // 2 x 64*32
  short* sVt = smem + 6144;    // 2 x 32*72
  short* sP = smem + 10752;    // 64*72

  const int sr = wave * 16 + (lane >> 2);      // staging row 0..63
  const int sgs = (lane & 3) ^ (sr & 3);       // swizzled source granule

  auto stageK = [&](int kt, int buf) {
    const short* src = QK + (size_t)((kt * 64 + sr) * 4 + b) * 512 + 256 + cb + sgs * 8;
    GLL16(src, sK + buf * 2048 + wave * 512);
  };
  const int vrow = tid >> 2, vdof = (tid & 3) * 8;
  const int vkp = vrow ^ (((vdof >> 3) & 3) << 4);
  auto loadV = [&](int kt) -> bf16x8 {
    int kk = kt * 64 + vrow;
    return (kk < NQ)
        ? *reinterpret_cast<const bf16x8*>(V + (size_t)(kk * 4 + b) * 256 + cb + vdof)
        : bzero8();
  };
  auto writeV = [&](bf16x8 vv, int buf) {
    short* dst = sVt + buf * 2304;
#pragma unroll
    for (int j = 0; j < 8; ++j) dst[(vdof + j) * 72 + vkp] = vv[j];
  };

  // prologue: Q + tile 0
  {
    const short* qsrc = QK + (size_t)((q0 + sr) * 4 + b) * 512 + cb + sgs * 8;
    GLL16(qsrc, sQ + wave * 512);
  }
  stageK(0, 0);
  {
    bf16x8 v0 = loadV(0);
    writeV(v0, 0);
  }
  __syncthreads();

  const int wr = wave * 16;
  const int rq = wr + l15;
  const bf16x8 aq = *reinterpret_cast<const bf16x8*>(&sQ[rq * 32 + ((l4 ^ (rq & 3)) * 8)]);

  float mrow[4], lrow[4];
#pragma unroll
  for (int i = 0; i < 4; ++i) { mrow[i] = -1e30f; lrow[i] = 0.f; }
  f32x4 accO[2];
  accO[0] = fzero4(); accO[1] = fzero4();

  const int pswz = (((wr >> 2) + l4) & 3) << 3;
  const int pswzr = (((wr >> 2) + (l15 >> 2)) & 3) << 3;

  for (int kt = 0; kt < 15; ++kt) {
    const int k0 = kt * 64;
    const int buf = kt & 1;
    const bool more = (kt + 1 < 15);
    bf16x8 vnext = bzero8();
    if (more) {
      stageK(kt + 1, buf ^ 1);   // async, lands by next barrier
      vnext = loadV(kt + 1);     // issue early; write after compute
    }

    f32x4 s[4];
#pragma unroll
    for (int f = 0; f < 4; ++f) {
      const int rb = f * 16 + l15;
      bf16x8 bk = *reinterpret_cast<bf16x8*>(
          &sK[buf * 2048 + rb * 32 + ((l4 ^ (rb & 3)) * 8)]);
      s[f] = __builtin_amdgcn_mfma_f32_16x16x32_bf16(aq, bk, fzero4(), 0, 0, 0);
    }
#pragma unroll
    for (int f = 0; f < 4; ++f) {
      bool valid = (k0 + f * 16 + l15) < NQ;
#pragma unroll
      for (int i = 0; i < 4; ++i) {
        float sv = s[f][i] * 0.17677669529663687f;
        s[f][i] = valid ? sv : -1e30f;
      }
    }
    float mx[4];
#pragma unroll
    for (int i = 0; i < 4; ++i)
      mx[i] = fmaxf(fmaxf(s[0][i], s[1][i]), fmaxf(s[2][i], s[3][i]));
#pragma unroll
    for (int off = 1; off < 16; off <<= 1)
#pragma unroll
      for (int i = 0; i < 4; ++i) mx[i] = fmaxf(mx[i], __shfl_xor(mx[i], off));

    float alpha[4], rs[4];
#pragma unroll
    for (int i = 0; i < 4; ++i) {
      float mn = fmaxf(mrow[i], mx[i]);
      alpha[i] = __expf(mrow[i] - mn);
      mrow[i] = mn;
      rs[i] = 0.f;
    }
#pragma unroll
    for (int f = 0; f < 4; ++f)
#pragma unroll
      for (int i = 0; i < 4; ++i) {
        float p = __expf(s[f][i] - mrow[i]);
        rs[i] += p;
        sP[(wr + l4 * 4 + i) * 72 + ((f * 16 + l15) ^ pswz)] = f2b(p);
      }
#pragma unroll
    for (int off = 1; off < 16; off <<= 1)
#pragma unroll
      for (int i = 0; i < 4; ++i) rs[i] += __shfl_xor(rs[i], off);
#pragma unroll
    for (int i = 0; i < 4; ++i) lrow[i] = lrow[i] * alpha[i] + rs[i];
#pragma unroll
    for (int nf = 0; nf < 2; ++nf)
#pragma unroll
      for (int i = 0; i < 4; ++i) accO[nf][i] *= alpha[i];

#pragma unroll
    for (int ks = 0; ks < 2; ++ks) {
      bf16x8 ap = *reinterpret_cast<bf16x8*>(
          &sP[(wr + l15) * 72 + ((ks * 32 + l4 * 8) ^ pswzr)]);
#pragma unroll
      for (int nf = 0; nf < 2; ++nf) {
        const int d = nf * 16 + l15;
        const int kb = (ks * 32 + l4 * 8) ^ (((d >> 3) & 3) << 4);
        bf16x8 bv = *reinterpret_cast<bf16x8*>(&sVt[buf * 2304 + d * 72 + kb]);
        accO[nf] = __builtin_amdgcn_mfma_f32_16x16x32_bf16(ap, bv, accO[nf], 0, 0, 0);
      }
    }
    if (more) writeV(vnext, buf ^ 1);
    __syncthreads();
  }

#pragma unroll
  for (int nf = 0; nf < 2; ++nf)
#pragma unroll
    for (int i = 0; i < 4; ++i) {
      int q = q0 + wr + l4 * 4 + i;
      if (q < NQ)
        O[(size_t)(q * 4 + b) * 256 + cb + nf * 16 + l15] = f2b(accO[nf][i] / lrow[i]);
    }
}

// ------------------------------------------------ value proj: 3-deep dual-gll + T4
// 3 LDS buffers, fully-unrolled K loop; steady-state vmcnt(8) waits for loads
// issued TWO iterations back. Pair-XCD mapping retained.
// LDS: sAf 3x8KB fp32 | sB 3x8KB bf16 = 48KB -> 3 blocks/CU.
__device__ __forceinline__ void value_core(const float* __restrict__ memory,
                                           const short* __restrict__ W,
                                           const float* __restrict__ vp_b,
                                           short* __restrict__ value, int vb,
                                           short* __restrict__ smem) {
  float* sAf = (float*)smem;       // 3 x 2048 floats
  short* sB = smem + 12288;        // 3 x 4096 shorts
  const int tid = threadIdx.x;
  const int wave = tid >> 6, lane = tid & 63;
  const int l15 = lane & 15, l4 = lane >> 4;
  const int wr = wave * 16;
  const int m0 = (((vb >> 4) << 3) | (vb & 7)) * 64;
  const int n0 = ((vb >> 3) & 1) * 128;

  const int ar0 = wave * 16 + (lane >> 3);
  const int ag = (lane & 7) ^ (lane >> 3);
  auto stageA = [&](int t, int buf) {
    const float* s0 = memory + (size_t)(m0 + ar0) * 256 + t * 32 + ag * 4;
    GLL16(s0, (short*)sAf + buf * 4096 + wave * 1024);
    const float* s1 = memory + (size_t)(m0 + ar0 + 8) * 256 + t * 32 + ag * 4;
    GLL16(s1, (short*)sAf + buf * 4096 + wave * 1024 + 512);
  };
  const int blr = wave * 16 + (lane >> 2);
  auto stageB = [&](int t, int buf) {
#pragma unroll
    for (int j = 0; j < 2; ++j) {
      int lr = j * 64 + blr;
      int gs = (lane & 3) ^ ((lr >> 1) & 3);
      const short* src = W + (size_t)(n0 + lr) * 256 + t * 32 + gs * 8;
      GLL16(src, sB + buf * 4096 + (j * 64 + wave * 16) * 32);
    }
  };

  f32x4 acc[8];
#pragma unroll
  for (int f = 0; f < 8; ++f) acc[f] = fzero4();

  auto compute = [&](int buf) {
    const int r = wr + l15;
    const int rx = r & 7;
    const float* ap = sAf + buf * 2048 + r * 32;
    float4 a0 = *reinterpret_cast<const float4*>(ap + (((2 * l4) ^ rx) * 4));
    float4 a1 = *reinterpret_cast<const float4*>(ap + (((2 * l4 + 1) ^ rx) * 4));
    bf16x8 av;
    av[0] = f2b(a0.x); av[1] = f2b(a0.y); av[2] = f2b(a0.z); av[3] = f2b(a0.w);
    av[4] = f2b(a1.x); av[5] = f2b(a1.y); av[6] = f2b(a1.z); av[7] = f2b(a1.w);
#pragma unroll
    for (int f = 0; f < 8; ++f) {
      const int rb = f * 16 + l15;
      bf16x8 bv = *reinterpret_cast<const bf16x8*>(
          &sB[buf * 4096 + rb * 32 + ((l4 ^ ((rb >> 1) & 3)) * 8)]);
      acc[f] = __builtin_amdgcn_mfma_f32_16x16x32_bf16(av, bv, acc[f], 0, 0, 0);
    }
  };

  // prologue: 3 tiles in flight; wait for tile 0 (allow newest 8 = tiles 1,2)
  stageA(0, 0); stageB(0, 0);
  stageA(1, 1); stageB(1, 1);
  stageA(2, 2); stageB(2, 2);
  asm volatile("s_waitcnt vmcnt(8)" ::: "memory");
  __builtin_amdgcn_sched_barrier(0);
  __builtin_amdgcn_s_barrier();
  __builtin_amdgcn_sched_barrier(0);

#pragma unroll
  for (int t = 0; t < 8; ++t) {
    const int buf = t % 3;
    compute(buf);
    // release slot: our ds_reads serviced, then all waves synced
    asm volatile("s_waitcnt lgkmcnt(0)" ::: "memory");
    __builtin_amdgcn_sched_barrier(0);
    __builtin_amdgcn_s_barrier();
    __builtin_amdgcn_sched_barrier(0);
    if (t + 3 < 8) { stageA(t + 3, buf); stageB(t + 3, buf); }
    if (t + 1 < 8) {
      // wait tile t+1 (issued 2 iterations ago); keep later tiles in flight
      if (t + 3 < 8)      asm volatile("s_waitcnt vmcnt(8)" ::: "memory");
      else if (t + 2 < 8) asm volatile("s_waitcnt vmcnt(4)" ::: "memory");
      else                asm volatile("s_waitcnt vmcnt(0)" ::: "memory");
      __builtin_amdgcn_sched_barrier(0);
      __builtin_amdgcn_s_barrier();
      __builtin_amdgcn_sched_barrier(0);
    }
  }

#pragma unroll
  for (int f = 0; f < 8; ++f) {
    const int col = n0 + f * 16 + l15;
    const float bb = vp_b[col];
#pragma unroll
    for (int i = 0; i < 4; ++i)
      value[(size_t)(m0 + wr + l4 * 4 + i) * 256 + col] = f2b(acc[f][i] + bb);
  }
}

// ------------------------------------------------ hetero: flash || value proj
__global__ __launch_bounds__(256) void flash_value(const short* __restrict__ QKb,
                                                   const short* __restrict__ Vb,
                                                   short* __restrict__ Ob,
                                                   const float* __restrict__ memory,
                                                   const short* __restrict__ Wvp,
                                                   const float* __restrict__ vp_b,
                                                   short* __restrict__ value) {
  __shared__ __align__(16) short smem[24576];  // 48KB -> 3 blocks/CU
  int bx = blockIdx.x;
  if (bx < 480) {
    flash_body(QKb, Vb, Ob, bx, smem);
  } else {
    value_core(memory, Wvp, vp_b, value, bx - 480, smem);
  }
}

// ------------------------------------------------ residual + LN (unfused variant)
__global__ __launch_bounds__(256) void ln_kernel(const float* __restrict__ A,
                                                 const float* __restrict__ B,
                                                 const float* __restrict__ g,
                                                 const float* __restrict__ bb,
                                                 float* __restrict__ outF,
                                                 short* __restrict__ outB,
                                                 const float* __restrict__ addv) {
  const int row = blockIdx.x;
  const int t = threadIdx.x;
  const size_t base = (size_t)row * D_MODEL;
  float x = A[base + t] + B[base + t];
  float s = x, s2 = x * x;
#pragma unroll
  for (int off = 32; off; off >>= 1) {
    s += __shfl_xor(s, off);
    s2 += __shfl_xor(s2, off);
  }
  __shared__ float wsum[4], wsum2[4];
  const int w = t >> 6;
  if ((t & 63) == 0) { wsum[w] = s; wsum2[w] = s2; }
  __syncthreads();
  s = wsum[0] + wsum[1] + wsum[2] + wsum[3];
  s2 = wsum2[0] + wsum2[1] + wsum2[2] + wsum2[3];
  const float mu = s * (1.f / 256.f);
  const float var = s2 * (1.f / 256.f) - mu * mu;
  const float inv = rsqrtf(var + 1e-5f);
  float y = (x - mu) * inv * g[t] + bb[t];
  outF[base + t] = y;
  if (outB) outB[base + t] = f2b(y + (addv ? addv[base + t] : 0.f));
}

// ------------------------------------------------ residual + LN over 4 partials
__global__ __launch_bounds__(256) void ln4_kernel(const float* __restrict__ A,
                                                  const float* __restrict__ P,
                                                  const float* __restrict__ g,
                                                  const float* __restrict__ bb,
                                                  float* __restrict__ outF) {
  const int row = blockIdx.x;
  const int t = threadIdx.x;
  const size_t base = (size_t)row * D_MODEL + t;
  const size_t stride = (size_t)MROWS * D_MODEL;
  float x = A[base] + P[base] + P[base + stride] + P[base + 2 * stride] + P[base + 3 * stride];
  float s = x, s2 = x * x;
#pragma unroll
  for (int off = 32; off; off >>= 1) {
    s += __shfl_xor(s, off);
    s2 += __shfl_xor(s2, off);
  }
  __shared__ float wsum[4], wsum2[4];
  const int w = t >> 6;
  if ((t & 63) == 0) { wsum[w] = s; wsum2[w] = s2; }
  __syncthreads();
  s = wsum[0] + wsum[1] + wsum[2] + wsum[3];
  s2 = wsum2[0] + wsum2[1] + wsum2[2] + wsum2[3];
  const float mu = s * (1.f / 256.f);
  const float var = s2 * (1.f / 256.f) - mu * mu;
  const float inv = rsqrtf(var + 1e-5f);
  outF[base] = (x - mu) * inv * g[t] + bb[t];
}

// ------------------------------------------------ MS-deform sampling (8-wide)
__global__ __launch_bounds__(256) void msds_kernel(const unsigned short* __restrict__ value,
                                                   const float* __restrict__ soaw,
                                                   const float* __restrict__ refp,
                                                   unsigned short* __restrict__ out) {
  const int tid = threadIdx.x;
  const int row = blockIdx.x * 8 + (tid >> 5);  // q*4+b
  const int lane32 = tid & 31;
  const int h = lane32 >> 2;
  const int dp = (lane32 & 3) * 8;
  const int b = row & 3;

  const int WL[4] = {128, 64, 32, 16};
  const int ST[4] = {0, 16384, 20480, 21504};

  const float* awp = soaw + (size_t)row * 384 + 256 + h * 16;
  float awv[16];
  float m = -1e30f;
#pragma unroll
  for (int i = 0; i < 16; ++i) { awv[i] = awp[i]; m = fmaxf(m, awv[i]); }
  float s = 0.f;
#pragma unroll
  for (int i = 0; i < 16; ++i) { awv[i] = __expf(awv[i] - m); s += awv[i]; }
  const float invs = 1.f / s;

  const float* offp = soaw + (size_t)row * 384 + h * 32;
  float acc[8];
#pragma unroll
  for (int j = 0; j < 8; ++j) acc[j] = 0.f;

#pragma unroll
  for (int l = 0; l < 4; ++l) {
    const int wl = WL[l], hl = WL[l], st = ST[l];
    const float rx = refp[((size_t)row * 4 + l) * 2 + 0];
    const float ry = refp[((size_t)row * 4 + l) * 2 + 1];
#pragma unroll
    for (int p = 0; p < 4; ++p) {
      const float ox = offp[l * 8 + p * 2 + 0];
      const float oy = offp[l * 8 + p * 2 + 1];
      const float x = (rx + ox / (float)wl) * (float)wl - 0.5f;
      const float y = (ry + oy / (float)hl) * (float)hl - 0.5f;
      const float x0f = floorf(x), y0f = floorf(y);
      const int x0 = (int)x0f, y0 = (int)y0f;
      const float fx = x - x0f, fy = y - y0f;
      const float a = awv[l * 4 + p] * invs;
      const float w00 = (1.f - fx) * (1.f - fy);
      const float w10 = fx * (1.f - fy);
      const float w01 = (1.f - fx) * fy;
      const float w11 = fx * fy;
      float sv[8];
#pragma unroll
      for (int j = 0; j < 8; ++j) sv[j] = 0.f;
      auto gat = [&](int ix, int iy, float wgt) {
        if (ix >= 0 && ix < wl && iy >= 0 && iy < hl) {
          const unsigned short* p2 =
              value + ((size_t)((st + iy * wl + ix) * 4 + b)) * 256 + h * 32 + dp;
          bf16x8 u = *reinterpret_cast<const bf16x8*>(p2);
#pragma unroll
          for (int j = 0; j < 8; ++j) sv[j] += wgt * bu2f((unsigned short)u[j]);
        }
      };
      gat(x0, y0, w00);
      gat(x0 + 1, y0, w10);
      gat(x0, y0 + 1, w01);
      gat(x0 + 1, y0 + 1, w11);
#pragma unroll
      for (int j = 0; j < 8; ++j) acc[j] += a * sv[j];
    }
  }
  bf16x8 o;
#pragma unroll
  for (int j = 0; j < 8; ++j) o[j] = f2b(acc[j]);
  *reinterpret_cast<bf16x8*>(&out[(size_t)row * 256 + h * 32 + dp]) = o;
}

// ---------------------------------------------------------------- launch
extern "C" void kernel_launch(void* const* d_in, const int* in_sizes, int n_in,
                              void* d_out, int out_size, void* d_ws, size_t ws_size,
                              hipStream_t stream) {
  const float* tgt      = (const float*)d_in[0];
  const float* qpos     = (const float*)d_in[1];
  const float* memory   = (const float*)d_in[2];
  const float* refp     = (const float*)d_in[3];
  const float* sa_in_w  = (const float*)d_in[4];
  const float* sa_in_b  = (const float*)d_in[5];
  const float* sa_out_w = (const float*)d_in[6];
  const float* sa_out_b = (const float*)d_in[7];
  const float* ln1_g = (const float*)d_in[8];
  const float* ln1_b = (const float*)d_in[9];
  const float* ln2_g = (const float*)d_in[10];
  const float* ln2_b = (const float*)d_in[11];
  const float* ln3_g = (const float*)d_in[12];
  const float* ln3_b = (const float*)d_in[13];
  const float* so_w = (const float*)d_in[14];
  const float* so_b = (const float*)d_in[15];
  const float* aw_w = (const float*)d_in[16];
  const float* aw_b = (const float*)d_in[17];
  const float* vp_w = (const float*)d_in[18];
  const float* vp_b = (const float*)d_in[19];
  const float* op_w = (const float*)d_in[20];
  const float* op_b = (const float*)d_in[21];
  const float* ff1_w = (const float*)d_in[22];
  const float* ff1_b = (const float*)d_in[23];
  const float* ff2_w = (const float*)d_in[24];
  const float* ff2_b = (const float*)d_in[25];

  float* out = (float*)d_out;
  float* ws = (float*)d_ws;

  short* Wb       = (short*)ws;                 // 1,540,096 shorts
  float* biasSOAW = ws + 770048;
  short* tgtb   = (short*)(ws + 770432);
  short* qkb    = (short*)(ws + 1231232);
  short* QKb    = (short*)(ws + 1692032);
  short* Vb     = (short*)(ws + 2613632);
  short* Ob     = (short*)(ws + 3074432);
  float* SA     = ws + 3535232;                 // (unused now)
  float* F      = ws + 4456832;
  short* qk2b   = (short*)(ws + 5378432);
  float* SOAW   = ws + 5839232;
  short* value  = (short*)(ws + 7221632);       // 11,141,120 shorts
  short* sampled= (short*)(ws + 18362752);
  float* CA     = ws + 18823552;                // (unused now)
  float* tgt3   = ws + 19745152;
  short* tgt3b  = (short*)(ws + 20666752);
  short* H      = (short*)(ws + 21127552);
  float* FFp    = ws + 7221632;                 // reuse value region after msds

  const short* Wqkv = Wb;
  const short* Wsa  = Wb + 196608;
  const short* Wso  = Wb + 262144;
  const short* Wvp  = Wb + 360448;
  const short* Wop  = Wb + 425984;
  const short* Wff1 = Wb + 491520;
  const short* Wff2 = Wb + 1015808;

  // 0. weights + activations prep (one dispatch)
  prep_all<<<9616, 256, 0, stream>>>(sa_in_w, sa_out_w, so_w, aw_w, vp_w, op_w,
                                     ff1_w, ff2_w, Wb, tgt, qpos, tgtb, qkb,
                                     so_b, aw_b, biasSOAW);
  // 1. q|k + v projections (hetero, 684 blocks)
  qkv_gemm<<<684, 256, 0, stream>>>(qkb, tgtb, Wqkv, sa_in_b, QKb, Vb);
  // 2. flash attention || value projection (480 flash + 2720 value = 3200)
  flash_value<<<3200, 256, 0, stream>>>(QKb, Vb, Ob, memory, Wvp, vp_b, value);
  // 3. fused: sa out projection + residual(tgt) + LN2 -> F, qk2b(+qpos)
  gemm_ln<<<57, 256, 0, stream>>>(Ob, Wsa, sa_out_b, tgt, ln2_g, ln2_b,
                                  F, qk2b, qpos);
  // 4. so|aw projection (N=384, fp32 out)
  gemm2<64, 0, 1, 0><<<dim3(57, 6), 256, 0, stream>>>(qk2b, Wso, biasSOAW, SOAW, MROWS, 384, 256);
  // 5. deformable sampling (8 rows/block)
  msds_kernel<<<450, 256, 0, stream>>>((const unsigned short*)value, SOAW, refp,
                                       (unsigned short*)sampled);
  // 6. fused: output projection + residual(F) + LN1 -> tgt3, tgt3b
  gemm_ln<<<57, 256, 0, stream>>>(sampled, Wop, op_b, F, ln1_g, ln1_b,
                                  tgt3, tgt3b, nullptr);
  // 7. FFN
  gemm2<64, 0, 0, 1><<<dim3(57, 32), 256, 0, stream>>>(tgt3b, Wff1, ff1_b, H, MROWS, 2048, 256);
  gemm_splitk<<<dim3(57, 4, 4), 256, 0, stream>>>(H, Wff2, ff2_b, FFp, MROWS, 256, 2048);
  // 8. out = LN(tgt3 + sum of 4 ff partials) [ln3]
  ln4_kernel<<<MROWS, 256, 0, stream>>>(tgt3, FFp, ln3_g, ln3_b, out);
}

// Round 15
// 161.173 us; speedup vs baseline: 1.2125x; 1.2125x over previous
//
#include <hip/hip_runtime.h>
#include <hip/hip_bf16.h>

#define D_MODEL 256
#define N_HEADS 8
#define HD 32
#define NQ 900
#define BS 4
#define MROWS (NQ * BS)          // 3600
#define HW_TOT 21760
#define VROWS (HW_TOT * BS)      // 87040

typedef __attribute__((ext_vector_type(8))) short bf16x8;
typedef __attribute__((ext_vector_type(4))) float f32x4;

__device__ inline short f2b(float f) {
  union { __hip_bfloat16 h; short s; } u;
  u.h = __float2bfloat16(f);
  return u.s;
}
__device__ inline float bu2f(unsigned short u) {
  union { unsigned int i; float f; } c;
  c.i = ((unsigned int)u) << 16;
  return c.f;
}
__device__ inline bf16x8 bzero8() {
  bf16x8 v;
#pragma unroll
  for (int j = 0; j < 8; ++j) v[j] = 0;
  return v;
}
__device__ inline f32x4 fzero4() {
  f32x4 v;
#pragma unroll
  for (int j = 0; j < 4; ++j) v[j] = 0.f;
  return v;
}

// async global->LDS, 16B per lane: lds dest = base + lane*16 (wave-uniform base)
#define GLL16(gsrc, ldst)                                                     \
  __builtin_amdgcn_global_load_lds(                                           \
      (__attribute__((address_space(1))) void*)(gsrc),                        \
      (__attribute__((address_space(3))) void*)(ldst), 16, 0, 0)

// ------------------------------------------------ prep: weights + activations
__global__ __launch_bounds__(256) void prep_all(const float* __restrict__ s0,
                                                const float* __restrict__ s1,
                                                const float* __restrict__ s2,
                                                const float* __restrict__ s3,
                                                const float* __restrict__ s4,
                                                const float* __restrict__ s5,
                                                const float* __restrict__ s6,
                                                const float* __restrict__ s7,
                                                short* __restrict__ dst,
                                                const float* __restrict__ tgt,
                                                const float* __restrict__ qpos,
                                                short* __restrict__ tgtb,
                                                short* __restrict__ qkb,
                                                const float* __restrict__ so_b,
                                                const float* __restrict__ aw_b,
                                                float* __restrict__ biasSOAW) {
  int i = blockIdx.x * 256 + threadIdx.x;
  if (i < 1540096) {
    const float* s; int off;
    if (i < 196608)      { s = s0; off = 0; }
    else if (i < 262144) { s = s1; off = 196608; }
    else if (i < 327680) { s = s2; off = 262144; }
    else if (i < 360448) { s = s3; off = 327680; }
    else if (i < 425984) { s = s4; off = 360448; }
    else if (i < 491520) { s = s5; off = 425984; }
    else if (i < 1015808){ s = s6; off = 491520; }
    else                 { s = s7; off = 1015808; }
    dst[i] = f2b(s[i - off]);
  } else {
    int j = i - 1540096;  // < 921600
    float t = tgt[j], p = qpos[j];
    tgtb[j] = f2b(t);
    qkb[j] = f2b(t + p);
    if (j < 384) biasSOAW[j] = (j < 256) ? so_b[j] : aw_b[j - 256];
  }
}

// ------------------------------------------------ GEMM core (BM=64, gll staging)
template <int BN, int AF32, int OUTF32, int RELU>
__device__ __forceinline__ void gemm_core(const void* __restrict__ Xv,
                                          const short* __restrict__ W,
                                          const float* __restrict__ bias,
                                          void* __restrict__ outv,
                                          int M, int N, int K, int m0, int n0,
                                          int t0, int t1, int addBias,
                                          short* __restrict__ smem) {
  constexpr int NF = BN / 16;
  short* sA = smem;                // 2 x 64*32
  short* sB = smem + 2 * 2048;     // 2 x BN*32
  const int tid = threadIdx.x;
  const int wave = tid >> 6, lane = tid & 63;
  const int l15 = lane & 15, l4 = lane >> 4;
  const int wr = wave * 16;
  const float* Xf = (const float*)Xv;
  const short* Xh = (const short*)Xv;

  f32x4 acc[NF];
#pragma unroll
  for (int f = 0; f < NF; ++f) acc[f] = fzero4();

  const int alr = wave * 16 + (lane >> 2);
  const int ags = (lane & 3) ^ ((alr >> 1) & 3);
  const int arow = tid >> 2, ak = tid & 3;
  const int agsrc = ak ^ ((arow >> 1) & 3);
  float4 ra0, ra1;

  auto stageB = [&](int t, int buf) {
    short* bb = sB + buf * BN * 32;
#pragma unroll
    for (int j = 0; j < BN / 64; ++j) {
      int lr = j * 64 + alr;
      int gs = (lane & 3) ^ ((lr >> 1) & 3);
      const short* src = W + (size_t)(n0 + lr) * K + t * 32 + gs * 8;
      GLL16(src, bb + (j * 64 + wave * 16) * 32);
    }
  };
  auto stageA_gll = [&](int t, int buf) {
    const short* src = Xh + (size_t)(m0 + alr) * K + t * 32 + ags * 8;
    GLL16(src, sA + buf * 2048 + wave * 512);
  };
  auto loadA_f32 = [&](int t) {
    const float* p = Xf + (size_t)(m0 + arow) * K + t * 32 + agsrc * 8;
    ra0 = *reinterpret_cast<const float4*>(p);
    ra1 = *reinterpret_cast<const float4*>(p + 4);
  };
  auto writeA_f32 = [&](int buf) {
    bf16x8 v;
    v[0] = f2b(ra0.x); v[1] = f2b(ra0.y); v[2] = f2b(ra0.z); v[3] = f2b(ra0.w);
    v[4] = f2b(ra1.x); v[5] = f2b(ra1.y); v[6] = f2b(ra1.z); v[7] = f2b(ra1.w);
    *reinterpret_cast<bf16x8*>(&sA[buf * 2048 + arow * 32 + ak * 8]) = v;
  };
  auto compute = [&](int buf) {
    const int r = wr + l15;
    bf16x8 av = *reinterpret_cast<const bf16x8*>(
        &sA[buf * 2048 + r * 32 + ((l4 ^ ((r >> 1) & 3)) * 8)]);
#pragma unroll
    for (int f = 0; f < NF; ++f) {
      const int rb = f * 16 + l15;
      bf16x8 bv = *reinterpret_cast<const bf16x8*>(
          &sB[buf * BN * 32 + rb * 32 + ((l4 ^ ((rb >> 1) & 3)) * 8)]);
      acc[f] = __builtin_amdgcn_mfma_f32_16x16x32_bf16(av, bv, acc[f], 0, 0, 0);
    }
  };

  if constexpr (AF32) { loadA_f32(t0); writeA_f32(0); }
  else stageA_gll(t0, 0);
  stageB(t0, 0);
  __syncthreads();

  int buf = 0;
  for (int t = t0; t < t1; ++t) {
    if (t + 1 < t1) {
      if constexpr (AF32) loadA_f32(t + 1);
      else stageA_gll(t + 1, buf ^ 1);
      stageB(t + 1, buf ^ 1);
    }
    compute(buf);
    if (AF32 && t + 1 < t1) writeA_f32(buf ^ 1);
    __syncthreads();
    buf ^= 1;
  }

#pragma unroll
  for (int f = 0; f < NF; ++f) {
    int col = n0 + f * 16 + l15;
    float bfv = addBias ? bias[col] : 0.f;
#pragma unroll
    for (int i = 0; i < 4; ++i) {
      int row = m0 + wr + l4 * 4 + i;
      if (row >= M) continue;
      float v = acc[f][i] + bfv;
      if (RELU) v = fmaxf(v, 0.f);
      if constexpr (OUTF32)
        ((float*)outv)[(size_t)row * N + col] = v;
      else
        ((short*)outv)[(size_t)row * N + col] = f2b(v);
    }
  }
}

template <int BN, int AF32, int OUTF32, int RELU>
__global__ __launch_bounds__(256) void gemm2(const void* __restrict__ Xv,
                                             const short* __restrict__ W,
                                             const float* __restrict__ bias,
                                             void* __restrict__ outv,
                                             int M, int N, int K) {
  __shared__ __align__(16) short smem[2 * 2048 + 2 * BN * 32];
  gemm_core<BN, AF32, OUTF32, RELU>(Xv, W, bias, outv, M, N, K,
                                    blockIdx.x * 64, blockIdx.y * BN,
                                    0, K / 32, 1, smem);
}

// ff2 split-K (2 chunks): blockIdx.z = K-chunk; fp32 partials (bias in chunk 0)
__global__ __launch_bounds__(256) void gemm_splitk(const void* __restrict__ Xv,
                                                   const short* __restrict__ W,
                                                   const float* __restrict__ bias,
                                                   float* __restrict__ outp,
                                                   int M, int N, int K) {
  __shared__ __align__(16) short smem[2 * 2048 + 2 * 64 * 32];
  const int kc = blockIdx.z;
  const int ntc = K / 32 / 2;
  gemm_core<64, 0, 1, 0>(Xv, W, bias, outp + (size_t)kc * M * N, M, N, K,
                         blockIdx.x * 64, blockIdx.y * 64,
                         kc * ntc, (kc + 1) * ntc, kc == 0, smem);
}

// ------------------------------------------------ q|k and v projections, one dispatch
__global__ __launch_bounds__(256) void qkv_gemm(const short* __restrict__ qkb,
                                                const short* __restrict__ tgtb,
                                                const short* __restrict__ Wqkv,
                                                const float* __restrict__ sa_in_b,
                                                short* __restrict__ QKb,
                                                short* __restrict__ Vb) {
  __shared__ __align__(16) short smem[2 * 2048 + 2 * 64 * 32];
  int bx = blockIdx.x;
  if (bx < 456) {
    gemm_core<64, 0, 0, 0>(qkb, Wqkv, sa_in_b, QKb, MROWS, 512, 256,
                           (bx % 57) * 64, (bx / 57) * 64, 0, 8, 1, smem);
  } else {
    bx -= 456;
    gemm_core<64, 0, 0, 0>(tgtb, Wqkv + 512 * 256, sa_in_b + 512, Vb, MROWS, 256, 256,
                           (bx % 57) * 64, (bx / 57) * 64, 0, 8, 1, smem);
  }
}

// ------------------------------------------------ flash attention body v2
// LDS: sQ 2048 | sK 2x2048 | sVt 2x2304 | sP 4608  = 15360 shorts (30.7KB)
__device__ __forceinline__ void flash_body(const short* __restrict__ QK,
                                           const short* __restrict__ V,
                                           short* __restrict__ O,
                                           int bid, short* __restrict__ smem) {
  const int bh = bid & 31, b = bh >> 3, h = bh & 7;
  const int q0 = (bid >> 5) * 64;
  const int tid = threadIdx.x, wave = tid >> 6, lane = tid & 63;
  const int l15 = lane & 15, l4 = lane >> 4;
  const int cb = h * 32;

  short* sQ = smem;            // 64*32
  short* sK = smem + 2048;     // 2 x 64*32
  short* sVt = smem + 6144;    // 2 x 32*72
  short* sP = smem + 10752;    // 64*72

  const int sr = wave * 16 + (lane >> 2);      // staging row 0..63
  const int sgs = (lane & 3) ^ (sr & 3);       // swizzled source granule

  auto stageK = [&](int kt, int buf) {
    const short* src = QK + (size_t)((kt * 64 + sr) * 4 + b) * 512 + 256 + cb + sgs * 8;
    GLL16(src, sK + buf * 2048 + wave * 512);
  };
  const int vrow = tid >> 2, vdof = (tid & 3) * 8;
  const int vkp = vrow ^ (((vdof >> 3) & 3) << 4);
  auto loadV = [&](int kt) -> bf16x8 {
    int kk = kt * 64 + vrow;
    return (kk < NQ)
        ? *reinterpret_cast<const bf16x8*>(V + (size_t)(kk * 4 + b) * 256 + cb + vdof)
        : bzero8();
  };
  auto writeV = [&](bf16x8 vv, int buf) {
    short* dst = sVt + buf * 2304;
#pragma unroll
    for (int j = 0; j < 8; ++j) dst[(vdof + j) * 72 + vkp] = vv[j];
  };

  // prologue: Q + tile 0
  {
    const short* qsrc = QK + (size_t)((q0 + sr) * 4 + b) * 512 + cb + sgs * 8;
    GLL16(qsrc, sQ + wave * 512);
  }
  stageK(0, 0);
  {
    bf16x8 v0 = loadV(0);
    writeV(v0, 0);
  }
  __syncthreads();

  const int wr = wave * 16;
  const int rq = wr + l15;
  const bf16x8 aq = *reinterpret_cast<const bf16x8*>(&sQ[rq * 32 + ((l4 ^ (rq & 3)) * 8)]);

  float mrow[4], lrow[4];
#pragma unroll
  for (int i = 0; i < 4; ++i) { mrow[i] = -1e30f; lrow[i] = 0.f; }
  f32x4 accO[2];
  accO[0] = fzero4(); accO[1] = fzero4();

  const int pswz = (((wr >> 2) + l4) & 3) << 3;
  const int pswzr = (((wr >> 2) + (l15 >> 2)) & 3) << 3;

  for (int kt = 0; kt < 15; ++kt) {
    const int k0 = kt * 64;
    const int buf = kt & 1;
    const bool more = (kt + 1 < 15);
    bf16x8 vnext = bzero8();
    if (more) {
      stageK(kt + 1, buf ^ 1);   // async, lands by next barrier
      vnext = loadV(kt + 1);     // issue early; write after compute
    }

    f32x4 s[4];
#pragma unroll
    for (int f = 0; f < 4; ++f) {
      const int rb = f * 16 + l15;
      bf16x8 bk = *reinterpret_cast<bf16x8*>(
          &sK[buf * 2048 + rb * 32 + ((l4 ^ (rb & 3)) * 8)]);
      s[f] = __builtin_amdgcn_mfma_f32_16x16x32_bf16(aq, bk, fzero4(), 0, 0, 0);
    }
#pragma unroll
    for (int f = 0; f < 4; ++f) {
      bool valid = (k0 + f * 16 + l15) < NQ;
#pragma unroll
      for (int i = 0; i < 4; ++i) {
        float sv = s[f][i] * 0.17677669529663687f;
        s[f][i] = valid ? sv : -1e30f;
      }
    }
    float mx[4];
#pragma unroll
    for (int i = 0; i < 4; ++i)
      mx[i] = fmaxf(fmaxf(s[0][i], s[1][i]), fmaxf(s[2][i], s[3][i]));
#pragma unroll
    for (int off = 1; off < 16; off <<= 1)
#pragma unroll
      for (int i = 0; i < 4; ++i) mx[i] = fmaxf(mx[i], __shfl_xor(mx[i], off));

    float alpha[4], rs[4];
#pragma unroll
    for (int i = 0; i < 4; ++i) {
      float mn = fmaxf(mrow[i], mx[i]);
      alpha[i] = __expf(mrow[i] - mn);
      mrow[i] = mn;
      rs[i] = 0.f;
    }
#pragma unroll
    for (int f = 0; f < 4; ++f)
#pragma unroll
      for (int i = 0; i < 4; ++i) {
        float p = __expf(s[f][i] - mrow[i]);
        rs[i] += p;
        sP[(wr + l4 * 4 + i) * 72 + ((f * 16 + l15) ^ pswz)] = f2b(p);
      }
#pragma unroll
    for (int off = 1; off < 16; off <<= 1)
#pragma unroll
      for (int i = 0; i < 4; ++i) rs[i] += __shfl_xor(rs[i], off);
#pragma unroll
    for (int i = 0; i < 4; ++i) lrow[i] = lrow[i] * alpha[i] + rs[i];
#pragma unroll
    for (int nf = 0; nf < 2; ++nf)
#pragma unroll
      for (int i = 0; i < 4; ++i) accO[nf][i] *= alpha[i];

#pragma unroll
    for (int ks = 0; ks < 2; ++ks) {
      bf16x8 ap = *reinterpret_cast<bf16x8*>(
          &sP[(wr + l15) * 72 + ((ks * 32 + l4 * 8) ^ pswzr)]);
#pragma unroll
      for (int nf = 0; nf < 2; ++nf) {
        const int d = nf * 16 + l15;
        const int kb = (ks * 32 + l4 * 8) ^ (((d >> 3) & 3) << 4);
        bf16x8 bv = *reinterpret_cast<bf16x8*>(&sVt[buf * 2304 + d * 72 + kb]);
        accO[nf] = __builtin_amdgcn_mfma_f32_16x16x32_bf16(ap, bv, accO[nf], 0, 0, 0);
      }
    }
    if (more) writeV(vnext, buf ^ 1);
    __syncthreads();
  }

#pragma unroll
  for (int nf = 0; nf < 2; ++nf)
#pragma unroll
    for (int i = 0; i < 4; ++i) {
      int q = q0 + wr + l4 * 4 + i;
      if (q < NQ)
        O[(size_t)(q * 4 + b) * 256 + cb + nf * 16 + l15] = f2b(accO[nf][i] / lrow[i]);
    }
}

// ------------------------------------------------ value proj: 2-deep dual-gll + T4
// counted vmcnt (never 0 mid-loop) + raw barriers; pair-XCD mapping.
// LDS: sAf 2x8KB fp32 | sB 2x8KB bf16 = 32KB -> 5 blocks/CU.
__device__ __forceinline__ void value_core(const float* __restrict__ memory,
                                           const short* __restrict__ W,
                                           const float* __restrict__ vp_b,
                                           short* __restrict__ value, int vb,
                                           short* __restrict__ smem) {
  float* sAf = (float*)smem;       // 2 x 2048 floats
  short* sB = smem + 8192;         // 2 x 4096 shorts
  const int tid = threadIdx.x;
  const int wave = tid >> 6, lane = tid & 63;
  const int l15 = lane & 15, l4 = lane >> 4;
  const int wr = wave * 16;
  const int m0 = (((vb >> 4) << 3) | (vb & 7)) * 64;
  const int n0 = ((vb >> 3) & 1) * 128;

  const int ar0 = wave * 16 + (lane >> 3);
  const int ag = (lane & 7) ^ (lane >> 3);
  auto stageA = [&](int t, int buf) {
    const float* s0 = memory + (size_t)(m0 + ar0) * 256 + t * 32 + ag * 4;
    GLL16(s0, (short*)sAf + buf * 4096 + wave * 1024);
    const float* s1 = memory + (size_t)(m0 + ar0 + 8) * 256 + t * 32 + ag * 4;
    GLL16(s1, (short*)sAf + buf * 4096 + wave * 1024 + 512);
  };
  const int blr = wave * 16 + (lane >> 2);
  auto stageB = [&](int t, int buf) {
#pragma unroll
    for (int j = 0; j < 2; ++j) {
      int lr = j * 64 + blr;
      int gs = (lane & 3) ^ ((lr >> 1) & 3);
      const short* src = W + (size_t)(n0 + lr) * 256 + t * 32 + gs * 8;
      GLL16(src, sB + buf * 4096 + (j * 64 + wave * 16) * 32);
    }
  };

  f32x4 acc[8];
#pragma unroll
  for (int f = 0; f < 8; ++f) acc[f] = fzero4();

  auto compute = [&](int buf) {
    const int r = wr + l15;
    const int rx = r & 7;
    const float* ap = sAf + buf * 2048 + r * 32;
    float4 a0 = *reinterpret_cast<const float4*>(ap + (((2 * l4) ^ rx) * 4));
    float4 a1 = *reinterpret_cast<const float4*>(ap + (((2 * l4 + 1) ^ rx) * 4));
    bf16x8 av;
    av[0] = f2b(a0.x); av[1] = f2b(a0.y); av[2] = f2b(a0.z); av[3] = f2b(a0.w);
    av[4] = f2b(a1.x); av[5] = f2b(a1.y); av[6] = f2b(a1.z); av[7] = f2b(a1.w);
#pragma unroll
    for (int f = 0; f < 8; ++f) {
      const int rb = f * 16 + l15;
      bf16x8 bv = *reinterpret_cast<const bf16x8*>(
          &sB[buf * 4096 + rb * 32 + ((l4 ^ ((rb >> 1) & 3)) * 8)]);
      acc[f] = __builtin_amdgcn_mfma_f32_16x16x32_bf16(av, bv, acc[f], 0, 0, 0);
    }
  };

  // prologue: 2 tiles in flight; wait only for tile 0 (4 newest = tile 1's)
  stageA(0, 0); stageB(0, 0);
  stageA(1, 1); stageB(1, 1);
  asm volatile("s_waitcnt vmcnt(4)" ::: "memory");
  __builtin_amdgcn_sched_barrier(0);
  __builtin_amdgcn_s_barrier();
  __builtin_amdgcn_sched_barrier(0);

#pragma unroll
  for (int t = 0; t < 8; ++t) {
    const int buf = t & 1;
    compute(buf);
    asm volatile("s_waitcnt lgkmcnt(0)" ::: "memory");
    __builtin_amdgcn_sched_barrier(0);
    __builtin_amdgcn_s_barrier();
    __builtin_amdgcn_sched_barrier(0);
    if (t + 2 < 8) { stageA(t + 2, buf); stageB(t + 2, buf); }
    if (t + 1 < 8) {
      if (t + 2 < 8) asm volatile("s_waitcnt vmcnt(4)" ::: "memory");
      else           asm volatile("s_waitcnt vmcnt(0)" ::: "memory");
      __builtin_amdgcn_sched_barrier(0);
      __builtin_amdgcn_s_barrier();
      __builtin_amdgcn_sched_barrier(0);
    }
  }

#pragma unroll
  for (int f = 0; f < 8; ++f) {
    const int col = n0 + f * 16 + l15;
    const float bb = vp_b[col];
#pragma unroll
    for (int i = 0; i < 4; ++i)
      value[(size_t)(m0 + wr + l4 * 4 + i) * 256 + col] = f2b(acc[f][i] + bb);
  }
}

// ------------------------------------------------ hetero: flash || value proj
__global__ __launch_bounds__(256) void flash_value(const short* __restrict__ QKb,
                                                   const short* __restrict__ Vb,
                                                   short* __restrict__ Ob,
                                                   const float* __restrict__ memory,
                                                   const short* __restrict__ Wvp,
                                                   const float* __restrict__ vp_b,
                                                   short* __restrict__ value) {
  __shared__ __align__(16) short smem[16384];  // 32KB -> 5 blocks/CU
  int bx = blockIdx.x;
  if (bx < 480) {
    flash_body(QKb, Vb, Ob, bx, smem);
  } else {
    value_core(memory, Wvp, vp_b, value, bx - 480, smem);
  }
}

// ------------------------------------------------ residual + LN (+fused bf16 out)
__global__ __launch_bounds__(256) void ln_kernel(const float* __restrict__ A,
                                                 const float* __restrict__ B,
                                                 const float* __restrict__ g,
                                                 const float* __restrict__ bb,
                                                 float* __restrict__ outF,
                                                 short* __restrict__ outB,
                                                 const float* __restrict__ addv) {
  const int row = blockIdx.x;
  const int t = threadIdx.x;
  const size_t base = (size_t)row * D_MODEL;
  float x = A[base + t] + B[base + t];
  float s = x, s2 = x * x;
#pragma unroll
  for (int off = 32; off; off >>= 1) {
    s += __shfl_xor(s, off);
    s2 += __shfl_xor(s2, off);
  }
  __shared__ float wsum[4], wsum2[4];
  const int w = t >> 6;
  if ((t & 63) == 0) { wsum[w] = s; wsum2[w] = s2; }
  __syncthreads();
  s = wsum[0] + wsum[1] + wsum[2] + wsum[3];
  s2 = wsum2[0] + wsum2[1] + wsum2[2] + wsum2[3];
  const float mu = s * (1.f / 256.f);
  const float var = s2 * (1.f / 256.f) - mu * mu;
  const float inv = rsqrtf(var + 1e-5f);
  float y = (x - mu) * inv * g[t] + bb[t];
  outF[base + t] = y;
  if (outB) outB[base + t] = f2b(y + (addv ? addv[base + t] : 0.f));
}

// ------------------------------------------------ residual + LN over 2 partials
__global__ __launch_bounds__(256) void ln4_kernel(const float* __restrict__ A,
                                                  const float* __restrict__ P,
                                                  const float* __restrict__ g,
                                                  const float* __restrict__ bb,
                                                  float* __restrict__ outF) {
  const int row = blockIdx.x;
  const int t = threadIdx.x;
  const size_t base = (size_t)row * D_MODEL + t;
  const size_t stride = (size_t)MROWS * D_MODEL;
  float x = A[base] + P[base] + P[base + stride];
  float s = x, s2 = x * x;
#pragma unroll
  for (int off = 32; off; off >>= 1) {
    s += __shfl_xor(s, off);
    s2 += __shfl_xor(s2, off);
  }
  __shared__ float wsum[4], wsum2[4];
  const int w = t >> 6;
  if ((t & 63) == 0) { wsum[w] = s; wsum2[w] = s2; }
  __syncthreads();
  s = wsum[0] + wsum[1] + wsum[2] + wsum[3];
  s2 = wsum2[0] + wsum2[1] + wsum2[2] + wsum2[3];
  const float mu = s * (1.f / 256.f);
  const float var = s2 * (1.f / 256.f) - mu * mu;
  const float inv = rsqrtf(var + 1e-5f);
  outF[base] = (x - mu) * inv * g[t] + bb[t];
}

// ------------------------------------------------ MS-deform sampling (8-wide)
__global__ __launch_bounds__(256) void msds_kernel(const unsigned short* __restrict__ value,
                                                   const float* __restrict__ soaw,
                                                   const float* __restrict__ refp,
                                                   unsigned short* __restrict__ out) {
  const int tid = threadIdx.x;
  const int row = blockIdx.x * 8 + (tid >> 5);  // q*4+b
  const int lane32 = tid & 31;
  const int h = lane32 >> 2;
  const int dp = (lane32 & 3) * 8;
  const int b = row & 3;

  const int WL[4] = {128, 64, 32, 16};
  const int ST[4] = {0, 16384, 20480, 21504};

  const float* awp = soaw + (size_t)row * 384 + 256 + h * 16;
  float awv[16];
  float m = -1e30f;
#pragma unroll
  for (int i = 0; i < 16; ++i) { awv[i] = awp[i]; m = fmaxf(m, awv[i]); }
  float s = 0.f;
#pragma unroll
  for (int i = 0; i < 16; ++i) { awv[i] = __expf(awv[i] - m); s += awv[i]; }
  const float invs = 1.f / s;

  const float* offp = soaw + (size_t)row * 384 + h * 32;
  float acc[8];
#pragma unroll
  for (int j = 0; j < 8; ++j) acc[j] = 0.f;

#pragma unroll
  for (int l = 0; l < 4; ++l) {
    const int wl = WL[l], hl = WL[l], st = ST[l];
    const float rx = refp[((size_t)row * 4 + l) * 2 + 0];
    const float ry = refp[((size_t)row * 4 + l) * 2 + 1];
#pragma unroll
    for (int p = 0; p < 4; ++p) {
      const float ox = offp[l * 8 + p * 2 + 0];
      const float oy = offp[l * 8 + p * 2 + 1];
      const float x = (rx + ox / (float)wl) * (float)wl - 0.5f;
      const float y = (ry + oy / (float)hl) * (float)hl - 0.5f;
      const float x0f = floorf(x), y0f = floorf(y);
      const int x0 = (int)x0f, y0 = (int)y0f;
      const float fx = x - x0f, fy = y - y0f;
      const float a = awv[l * 4 + p] * invs;
      const float w00 = (1.f - fx) * (1.f - fy);
      const float w10 = fx * (1.f - fy);
      const float w01 = (1.f - fx) * fy;
      const float w11 = fx * fy;
      float sv[8];
#pragma unroll
      for (int j = 0; j < 8; ++j) sv[j] = 0.f;
      auto gat = [&](int ix, int iy, float wgt) {
        if (ix >= 0 && ix < wl && iy >= 0 && iy < hl) {
          const unsigned short* p2 =
              value + ((size_t)((st + iy * wl + ix) * 4 + b)) * 256 + h * 32 + dp;
          bf16x8 u = *reinterpret_cast<const bf16x8*>(p2);
#pragma unroll
          for (int j = 0; j < 8; ++j) sv[j] += wgt * bu2f((unsigned short)u[j]);
        }
      };
      gat(x0, y0, w00);
      gat(x0 + 1, y0, w10);
      gat(x0, y0 + 1, w01);
      gat(x0 + 1, y0 + 1, w11);
#pragma unroll
      for (int j = 0; j < 8; ++j) acc[j] += a * sv[j];
    }
  }
  bf16x8 o;
#pragma unroll
  for (int j = 0; j < 8; ++j) o[j] = f2b(acc[j]);
  *reinterpret_cast<bf16x8*>(&out[(size_t)row * 256 + h * 32 + dp]) = o;
}

// ---------------------------------------------------------------- launch
extern "C" void kernel_launch(void* const* d_in, const int* in_sizes, int n_in,
                              void* d_out, int out_size, void* d_ws, size_t ws_size,
                              hipStream_t stream) {
  const float* tgt      = (const float*)d_in[0];
  const float* qpos     = (const float*)d_in[1];
  const float* memory   = (const float*)d_in[2];
  const float* refp     = (const float*)d_in[3];
  const float* sa_in_w  = (const float*)d_in[4];
  const float* sa_in_b  = (const float*)d_in[5];
  const float* sa_out_w = (const float*)d_in[6];
  const float* sa_out_b = (const float*)d_in[7];
  const float* ln1_g = (const float*)d_in[8];
  const float* ln1_b = (const float*)d_in[9];
  const float* ln2_g = (const float*)d_in[10];
  const float* ln2_b = (const float*)d_in[11];
  const float* ln3_g = (const float*)d_in[12];
  const float* ln3_b = (const float*)d_in[13];
  const float* so_w = (const float*)d_in[14];
  const float* so_b = (const float*)d_in[15];
  const float* aw_w = (const float*)d_in[16];
  const float* aw_b = (const float*)d_in[17];
  const float* vp_w = (const float*)d_in[18];
  const float* vp_b = (const float*)d_in[19];
  const float* op_w = (const float*)d_in[20];
  const float* op_b = (const float*)d_in[21];
  const float* ff1_w = (const float*)d_in[22];
  const float* ff1_b = (const float*)d_in[23];
  const float* ff2_w = (const float*)d_in[24];
  const float* ff2_b = (const float*)d_in[25];

  float* out = (float*)d_out;
  float* ws = (float*)d_ws;

  short* Wb       = (short*)ws;                 // 1,540,096 shorts
  float* biasSOAW = ws + 770048;
  short* tgtb   = (short*)(ws + 770432);
  short* qkb    = (short*)(ws + 1231232);
  short* QKb    = (short*)(ws + 1692032);
  short* Vb     = (short*)(ws + 2613632);
  short* Ob     = (short*)(ws + 3074432);
  float* SA     = ws + 3535232;
  float* F      = ws + 4456832;
  short* qk2b   = (short*)(ws + 5378432);
  float* SOAW   = ws + 5839232;
  short* value  = (short*)(ws + 7221632);       // 11,141,120 shorts
  short* sampled= (short*)(ws + 18362752);
  float* CA     = ws + 18823552;
  float* tgt3   = ws + 19745152;
  short* tgt3b  = (short*)(ws + 20666752);
  short* H      = (short*)(ws + 21127552);
  float* FFp    = ws + 7221632;                 // reuse value region after msds

  const short* Wqkv = Wb;
  const short* Wsa  = Wb + 196608;
  const short* Wso  = Wb + 262144;
  const short* Wvp  = Wb + 360448;
  const short* Wop  = Wb + 425984;
  const short* Wff1 = Wb + 491520;
  const short* Wff2 = Wb + 1015808;

  // 0. weights + activations prep (one dispatch)
  prep_all<<<9616, 256, 0, stream>>>(sa_in_w, sa_out_w, so_w, aw_w, vp_w, op_w,
                                     ff1_w, ff2_w, Wb, tgt, qpos, tgtb, qkb,
                                     so_b, aw_b, biasSOAW);
  // 1. q|k + v projections (hetero, 684 blocks)
  qkv_gemm<<<684, 256, 0, stream>>>(qkb, tgtb, Wqkv, sa_in_b, QKb, Vb);
  // 2. flash attention || value projection (480 flash + 2720 value = 3200)
  flash_value<<<3200, 256, 0, stream>>>(QKb, Vb, Ob, memory, Wvp, vp_b, value);
  // 3. sa out projection (fp32 out)
  gemm2<64, 0, 1, 0><<<dim3(57, 4), 256, 0, stream>>>(Ob, Wsa, sa_out_b, SA, MROWS, 256, 256);
  // 4. tgt2 = LN(tgt+sa) [ln2]; qk2b = bf16(tgt2+qpos)
  ln_kernel<<<MROWS, 256, 0, stream>>>(tgt, SA, ln2_g, ln2_b, F, qk2b, qpos);
  // 5. so|aw projection (N=384, fp32 out)
  gemm2<64, 0, 1, 0><<<dim3(57, 6), 256, 0, stream>>>(qk2b, Wso, biasSOAW, SOAW, MROWS, 384, 256);
  // 6. deformable sampling (8 rows/block)
  msds_kernel<<<450, 256, 0, stream>>>((const unsigned short*)value, SOAW, refp,
                                       (unsigned short*)sampled);
  // 7. output projection (fp32 out)
  gemm2<64, 0, 1, 0><<<dim3(57, 4), 256, 0, stream>>>(sampled, Wop, op_b, CA, MROWS, 256, 256);
  // 8. tgt3 = LN(tgt2 + ca) [ln1]
  ln_kernel<<<MROWS, 256, 0, stream>>>(F, CA, ln1_g, ln1_b, tgt3, tgt3b, nullptr);
  // 9. FFN
  gemm2<64, 0, 0, 1><<<dim3(57, 32), 256, 0, stream>>>(tgt3b, Wff1, ff1_b, H, MROWS, 2048, 256);
  gemm_splitk<<<dim3(57, 4, 2), 256, 0, stream>>>(H, Wff2, ff2_b, FFp, MROWS, 256, 2048);
  // 10. out = LN(tgt3 + sum of 2 ff partials) [ln3]
  ln4_kernel<<<MROWS, 256, 0, stream>>>(tgt3, FFp, ln3_g, ln3_b, out);
}